// Round 8
// baseline (104.374 us; speedup 1.0000x reference)
//
#include <hip/hip_runtime.h>

#define BB 128
#define NN 128
#define EE 32

// ws: float block-min slots at [0..255], slot = blockIdx.x of ltn_fused
// (b*2+half). Finalize kernel (separate dispatch) reduces them. No atomics,
// no init required (every slot is written by its block before finalize runs).

// ---------------------------------------------------------------------------
// Fused: grid 256 = 128 b x 2 i-halves; block 256 = 8 groups x 32 lanes.
// Phase A (encode, 2x redundant per batch): lane e of each group owns neuron
// e; weight COLUMNS in VGPRs (loaded once); h1/enc broadcast via 2 alternating
// private LDS rows per group (sw-pipelined, unroll 2). Each group encodes 16
// items -> hy/hx/iso directly into LDS.
// Phase B (pairs): each lane-group-of-8 handles 2 i's; hy rows read as b128.
// Phase C: block min -> plain store to ws[blockIdx.x].
// ---------------------------------------------------------------------------
__global__ __launch_bounds__(256) void ltn_fused(
    const float* __restrict__ boxes, const int* __restrict__ classes,
    const float* __restrict__ scores, const int* __restrict__ num_objects,
    const float* __restrict__ W1, const float* __restrict__ b1,
    const float* __restrict__ W2, const float* __restrict__ b2,
    const float* __restrict__ Wo1, const float* __restrict__ bo1,
    const float* __restrict__ Wo2, const float* __restrict__ bo2,
    const float* __restrict__ Ws1, const float* __restrict__ bs1,
    const float* __restrict__ Ws2, const float* __restrict__ bs2,
    float* __restrict__ ws)
{
    __shared__ float hyS[128 * 36];   // stride 36: rows 16B-aligned, conflict-free
    __shared__ float hxS[128 * 36];
    __shared__ float rows[16 * 36];   // 2 scratch rows per group (sw-pipeline)
    __shared__ float isoS[128];
    __shared__ float wred[4];

    const int t = threadIdx.x;
    const int b = blockIdx.x >> 1;
    const int half = blockIdx.x & 1;
    const int e = t & 31;
    const int g = t >> 5;              // group 0..7

    // ---- weight columns into VGPRs (coalesced dword loads, once) ----
    float w1c[6];
#pragma unroll
    for (int f = 0; f < 6; f++) w1c[f] = W1[f * 32 + e];
    float w2c[32], wo1c[32], wsxc[32], wsyc[32];
#pragma unroll
    for (int k = 0; k < 32; k++) {
        w2c[k]  = W2[k * 32 + e];
        wo1c[k] = Wo1[k * 32 + e];
        wsxc[k] = Ws1[k * 32 + e];
        wsyc[k] = Ws1[(32 + k) * 32 + e];
    }
    const float b1e  = b1[e];
    const float b2e  = b2[e];
    const float bo1e = bo1[e];
    const float wo2e = Wo2[e];
    const float bo2s = bo2[0];

    // ---------------- Phase A: encode 16 items per group ----------------
    const int il0 = g * 16;
#pragma unroll 2
    for (int it = 0; it < 16; ++it) {
        const int il = il0 + it;               // local item 0..127
        const int item = b * 128 + il;
        float* row = rows + (g * 2 + (it & 1)) * 36;

        const float4 bx = ((const float4*)boxes)[item];
        const float c4 = (float)classes[item];
        const float c5 = scores[item];

        // layer 1
        float h1 = b1e;
        h1 = fmaf(bx.x, w1c[0], h1);
        h1 = fmaf(bx.y, w1c[1], h1);
        h1 = fmaf(bx.z, w1c[2], h1);
        h1 = fmaf(bx.w, w1c[3], h1);
        h1 = fmaf(c4,   w1c[4], h1);
        h1 = fmaf(c5,   w1c[5], h1);
        h1 = fmaxf(h1, 0.f);

        row[e] = h1;                           // ds_write_b32

        // layer 2: enc = h1 @ W2 + b2 (broadcast reads, 4 chains)
        float a0 = 0.f, a1 = 0.f, a2 = 0.f, a3 = 0.f;
#pragma unroll
        for (int kk = 0; kk < 8; kk++) {
            const float4 h = *(const float4*)(row + kk * 4);
            a0 = fmaf(h.x, w2c[4 * kk + 0], a0);
            a1 = fmaf(h.y, w2c[4 * kk + 1], a1);
            a2 = fmaf(h.z, w2c[4 * kk + 2], a2);
            a3 = fmaf(h.w, w2c[4 * kk + 3], a3);
        }
        const float enc = ((a0 + a1) + (a2 + a3)) + b2e;
        row[e] = enc;   // wave order: all h1 reads above already issued

        // heads
        float u = bo1e, hx = 0.f, hy = 0.f;
#pragma unroll
        for (int kk = 0; kk < 8; kk++) {
            const float4 ec = *(const float4*)(row + kk * 4);
            const int k0 = 4 * kk;
            u  = fmaf(ec.x, wo1c[k0 + 0], u);
            u  = fmaf(ec.y, wo1c[k0 + 1], u);
            u  = fmaf(ec.z, wo1c[k0 + 2], u);
            u  = fmaf(ec.w, wo1c[k0 + 3], u);
            hx = fmaf(ec.x, wsxc[k0 + 0], hx);
            hx = fmaf(ec.y, wsxc[k0 + 1], hx);
            hx = fmaf(ec.z, wsxc[k0 + 2], hx);
            hx = fmaf(ec.w, wsxc[k0 + 3], hx);
            hy = fmaf(ec.x, wsyc[k0 + 0], hy);
            hy = fmaf(ec.y, wsyc[k0 + 1], hy);
            hy = fmaf(ec.z, wsyc[k0 + 2], hy);
            hy = fmaf(ec.w, wsyc[k0 + 3], hy);
        }
        u = fmaxf(u, 0.f);

        float v = u * wo2e;
        v += __shfl_xor(v, 16, 32);
        v += __shfl_xor(v, 8, 32);
        v += __shfl_xor(v, 4, 32);
        v += __shfl_xor(v, 2, 32);
        v += __shfl_xor(v, 1, 32);

        hyS[il * 36 + e] = hy;
        hxS[il * 36 + e] = hx;
        if (e == 0)
            isoS[il] = 1.f / (1.f + __expf(-(v + bo2s)));
    }
    __syncthreads();

    // ---------------- Phase B: pairs (2 i's per lane) ----------------
    const int nb = num_objects[b];
    const int p  = t >> 3;             // 0..31
    const int li0 = half * 64 + p * 2; // local i index
    const int li1 = li0 + 1;
    const int s  = t & 7;

    float hxb0[32], hxb1[32];
#pragma unroll
    for (int kk = 0; kk < 8; kk++) {
        const float4 a = ((const float4*)(hxS + li0 * 36))[kk];
        const float4 c = ((const float4*)(hxS + li1 * 36))[kk];
        const int k0 = 4 * kk;
        hxb0[k0 + 0] = a.x + bs1[k0 + 0];  hxb1[k0 + 0] = c.x + bs1[k0 + 0];
        hxb0[k0 + 1] = a.y + bs1[k0 + 1];  hxb1[k0 + 1] = c.y + bs1[k0 + 1];
        hxb0[k0 + 2] = a.z + bs1[k0 + 2];  hxb1[k0 + 2] = c.z + bs1[k0 + 2];
        hxb0[k0 + 3] = a.w + bs1[k0 + 3];  hxb1[k0 + 3] = c.w + bs1[k0 + 3];
    }
    float w2[32];
#pragma unroll
    for (int k = 0; k < 32; k++) w2[k] = Ws2[k];       // uniform -> s_load
    const float bbias = bs2[0];

    float acc0 = 0.f, acc1 = 0.f;
    for (int j = s; j < nb; j += 8) {
        const float4* hr4 = (const float4*)(hyS + j * 36);
        float d0 = bbias, d1 = 0.f, d2 = 0.f, d3 = 0.f;
        float e0 = bbias, e1 = 0.f, e2 = 0.f, e3 = 0.f;
#pragma unroll
        for (int kk = 0; kk < 8; kk++) {
            const float4 h = hr4[kk];
            const int k0 = 4 * kk;
            d0 = fmaf(fmaxf(hxb0[k0 + 0] + h.x, 0.f), w2[k0 + 0], d0);
            d1 = fmaf(fmaxf(hxb0[k0 + 1] + h.y, 0.f), w2[k0 + 1], d1);
            d2 = fmaf(fmaxf(hxb0[k0 + 2] + h.z, 0.f), w2[k0 + 2], d2);
            d3 = fmaf(fmaxf(hxb0[k0 + 3] + h.w, 0.f), w2[k0 + 3], d3);
            e0 = fmaf(fmaxf(hxb1[k0 + 0] + h.x, 0.f), w2[k0 + 0], e0);
            e1 = fmaf(fmaxf(hxb1[k0 + 1] + h.y, 0.f), w2[k0 + 1], e1);
            e2 = fmaf(fmaxf(hxb1[k0 + 2] + h.z, 0.f), w2[k0 + 2], e2);
            e3 = fmaf(fmaxf(hxb1[k0 + 3] + h.w, 0.f), w2[k0 + 3], e3);
        }
        const float dd = (d0 + d1) + (d2 + d3);
        const float ee = (e0 + e1) + (e2 + e3);
        const float same0 = 1.f / (1.f + __expf(-dd));
        const float same1 = 1.f / (1.f + __expf(-ee));
        const float iso_j = isoS[j];
        acc0 += fminf(iso_j, same0);
        acc1 += fminf(iso_j, same1);
    }
    acc0 += __shfl_xor(acc0, 1);  acc1 += __shfl_xor(acc1, 1);
    acc0 += __shfl_xor(acc0, 2);  acc1 += __shfl_xor(acc1, 2);
    acc0 += __shfl_xor(acc0, 4);  acc1 += __shfl_xor(acc1, 4);

    const float denom = (float)(nb > 1 ? nb : 1);
    const float ex0 = acc0 / denom;
    const float ex1 = acc1 / denom;
    const float o0 = fmaxf(1.f - isoS[li0], ex0);
    const float o1 = fmaxf(1.f - isoS[li1], ex1);
    float val = fminf((li0 < nb) ? o0 : 1.f, (li1 < nb) ? o1 : 1.f);

    // min over the wave, then block
    val = fminf(val, __shfl_xor(val, 8));
    val = fminf(val, __shfl_xor(val, 16));
    val = fminf(val, __shfl_xor(val, 32));
    if ((t & 63) == 0) wred[t >> 6] = val;
    __syncthreads();

    if (t == 0)
        ws[blockIdx.x] = fminf(fminf(wred[0], wred[1]), fminf(wred[2], wred[3]));
}

// ---------------------------------------------------------------------------
// Finalize: 1 block x 128 threads. sat_b = min of the two half-mins; mean over
// valid batches. Dispatch boundary guarantees visibility of ws stores.
// ---------------------------------------------------------------------------
__global__ __launch_bounds__(128) void finalize_kernel(
    const int* __restrict__ num_objects, const float* __restrict__ ws,
    float* __restrict__ out)
{
    __shared__ float r1[2], r2[2];
    const int t = threadIdx.x;        // 0..127 = batch
    const float sat = fminf(ws[2 * t], ws[2 * t + 1]);
    const float valid = (num_objects[t] > 0) ? 1.f : 0.f;
    float contrib = sat * valid;
    float vcnt = valid;
#pragma unroll
    for (int off = 1; off < 64; off <<= 1) {
        contrib += __shfl_xor(contrib, off);
        vcnt    += __shfl_xor(vcnt, off);
    }
    if ((t & 63) == 0) { r1[t >> 6] = contrib; r2[t >> 6] = vcnt; }
    __syncthreads();
    if (t == 0) {
        const float sc = r1[0] + r1[1];
        const float cn = r2[0] + r2[1];
        out[0] = (cn > 0.f) ? (sc / cn) : 1.f;
    }
}

extern "C" void kernel_launch(void* const* d_in, const int* in_sizes, int n_in,
                              void* d_out, int out_size, void* d_ws, size_t ws_size,
                              hipStream_t stream)
{
    const float* boxes       = (const float*)d_in[0];
    const int*   classes     = (const int*)d_in[1];
    const float* scores      = (const float*)d_in[2];
    const int*   num_objects = (const int*)d_in[3];
    const float* W1  = (const float*)d_in[4];
    const float* b1  = (const float*)d_in[5];
    const float* W2  = (const float*)d_in[6];
    const float* b2  = (const float*)d_in[7];
    const float* Wo1 = (const float*)d_in[8];
    const float* bo1 = (const float*)d_in[9];
    const float* Wo2 = (const float*)d_in[10];
    const float* bo2 = (const float*)d_in[11];
    const float* Ws1 = (const float*)d_in[12];
    const float* bs1 = (const float*)d_in[13];
    const float* Ws2 = (const float*)d_in[14];
    const float* bs2 = (const float*)d_in[15];

    float* ws  = (float*)d_ws;
    float* out = (float*)d_out;

    ltn_fused<<<256, 256, 0, stream>>>(boxes, classes, scores, num_objects,
                                       W1, b1, W2, b2, Wo1, bo1, Wo2, bo2,
                                       Ws1, bs1, Ws2, bs2, ws);
    finalize_kernel<<<1, 128, 0, stream>>>(num_objects, ws, out);
}

// Round 9
// 100.546 us; speedup vs baseline: 1.0381x; 1.0381x over previous
//
#include <hip/hip_runtime.h>

#define BB 128
#define NN 128
#define EE 32

// ws: float block-min slots [0..255], slot = blockIdx.x of ltn_fused
// (= b*2 + half). finalize_kernel (2nd dispatch) reduces them; dispatch
// boundary guarantees visibility. No atomics, no ws init needed.

// ---------------------------------------------------------------------------
// Fused: grid 256 = 128 b x 2 i-halves; block 512 = 16 groups x 32 lanes
// (8 waves -> 2 waves/SIMD for latency hiding; r8's 256-thr block was 1/SIMD).
// Phase A (encode, 2x redundant chip-wide): lane e owns neuron e; weight
// COLUMNS in VGPRs (loaded once); h1/enc broadcast via 2 alternating private
// LDS rows per group; each group encodes 8 items into hyS/hxS/isoS.
// Phase B (pairs): 1 i per lane (p = t>>3), 8 j-lanes; hy rows as ds_read_b128.
// Phase C: block min -> plain store ws[blockIdx.x].
// ---------------------------------------------------------------------------
__global__ __launch_bounds__(512) void ltn_fused(
    const float* __restrict__ boxes, const int* __restrict__ classes,
    const float* __restrict__ scores, const int* __restrict__ num_objects,
    const float* __restrict__ W1, const float* __restrict__ b1,
    const float* __restrict__ W2, const float* __restrict__ b2,
    const float* __restrict__ Wo1, const float* __restrict__ bo1,
    const float* __restrict__ Wo2, const float* __restrict__ bo2,
    const float* __restrict__ Ws1, const float* __restrict__ bs1,
    const float* __restrict__ Ws2, const float* __restrict__ bs2,
    float* __restrict__ ws)
{
    __shared__ float hyS[128 * 36];   // stride 36: rows 16B-aligned, conflict-free
    __shared__ float hxS[128 * 36];
    __shared__ float rows[32 * 36];   // 2 scratch rows per group (sw-pipeline)
    __shared__ float isoS[128];
    __shared__ float wred[8];

    const int t = threadIdx.x;
    const int b = blockIdx.x >> 1;
    const int half = blockIdx.x & 1;
    const int e = t & 31;
    const int g = t >> 5;              // group 0..15

    // ---- weight columns into VGPRs (coalesced dword loads, once) ----
    float w1c[6];
#pragma unroll
    for (int f = 0; f < 6; f++) w1c[f] = W1[f * 32 + e];
    float w2c[32], wo1c[32], wsxc[32], wsyc[32];
#pragma unroll
    for (int k = 0; k < 32; k++) {
        w2c[k]  = W2[k * 32 + e];
        wo1c[k] = Wo1[k * 32 + e];
        wsxc[k] = Ws1[k * 32 + e];
        wsyc[k] = Ws1[(32 + k) * 32 + e];
    }
    const float b1e  = b1[e];
    const float b2e  = b2[e];
    const float bo1e = bo1[e];
    const float wo2e = Wo2[e];
    const float bo2s = bo2[0];

    // ---------------- Phase A: encode 8 items per group ----------------
    const int il0 = g * 8;
#pragma unroll 2
    for (int it = 0; it < 8; ++it) {
        const int il = il0 + it;               // local item 0..127
        const int item = b * 128 + il;
        float* row = rows + (g * 2 + (it & 1)) * 36;

        const float4 bx = ((const float4*)boxes)[item];
        const float c4 = (float)classes[item];
        const float c5 = scores[item];

        // layer 1
        float h1 = b1e;
        h1 = fmaf(bx.x, w1c[0], h1);
        h1 = fmaf(bx.y, w1c[1], h1);
        h1 = fmaf(bx.z, w1c[2], h1);
        h1 = fmaf(bx.w, w1c[3], h1);
        h1 = fmaf(c4,   w1c[4], h1);
        h1 = fmaf(c5,   w1c[5], h1);
        h1 = fmaxf(h1, 0.f);

        row[e] = h1;                           // ds_write_b32

        // layer 2: enc = h1 @ W2 + b2 (broadcast reads, 4 chains)
        float a0 = 0.f, a1 = 0.f, a2 = 0.f, a3 = 0.f;
#pragma unroll
        for (int kk = 0; kk < 8; kk++) {
            const float4 h = *(const float4*)(row + kk * 4);
            a0 = fmaf(h.x, w2c[4 * kk + 0], a0);
            a1 = fmaf(h.y, w2c[4 * kk + 1], a1);
            a2 = fmaf(h.z, w2c[4 * kk + 2], a2);
            a3 = fmaf(h.w, w2c[4 * kk + 3], a3);
        }
        const float enc = ((a0 + a1) + (a2 + a3)) + b2e;
        row[e] = enc;   // wave order: all h1 reads above already issued

        // heads
        float u = bo1e, hx = 0.f, hy = 0.f;
#pragma unroll
        for (int kk = 0; kk < 8; kk++) {
            const float4 ec = *(const float4*)(row + kk * 4);
            const int k0 = 4 * kk;
            u  = fmaf(ec.x, wo1c[k0 + 0], u);
            u  = fmaf(ec.y, wo1c[k0 + 1], u);
            u  = fmaf(ec.z, wo1c[k0 + 2], u);
            u  = fmaf(ec.w, wo1c[k0 + 3], u);
            hx = fmaf(ec.x, wsxc[k0 + 0], hx);
            hx = fmaf(ec.y, wsxc[k0 + 1], hx);
            hx = fmaf(ec.z, wsxc[k0 + 2], hx);
            hx = fmaf(ec.w, wsxc[k0 + 3], hx);
            hy = fmaf(ec.x, wsyc[k0 + 0], hy);
            hy = fmaf(ec.y, wsyc[k0 + 1], hy);
            hy = fmaf(ec.z, wsyc[k0 + 2], hy);
            hy = fmaf(ec.w, wsyc[k0 + 3], hy);
        }
        u = fmaxf(u, 0.f);

        float v = u * wo2e;
        v += __shfl_xor(v, 16, 32);
        v += __shfl_xor(v, 8, 32);
        v += __shfl_xor(v, 4, 32);
        v += __shfl_xor(v, 2, 32);
        v += __shfl_xor(v, 1, 32);

        hyS[il * 36 + e] = hy;
        hxS[il * 36 + e] = hx;
        if (e == 0)
            isoS[il] = 1.f / (1.f + __expf(-(v + bo2s)));
    }
    __syncthreads();

    // ---------------- Phase B: pairs (1 i per lane) ----------------
    const int nb = num_objects[b];
    const int p  = t >> 3;             // 0..63
    const int li = half * 64 + p;      // local i index
    const int s  = t & 7;

    float hxb[32];
#pragma unroll
    for (int kk = 0; kk < 8; kk++) {
        const float4 a = ((const float4*)(hxS + li * 36))[kk];
        const int k0 = 4 * kk;
        hxb[k0 + 0] = a.x + bs1[k0 + 0];
        hxb[k0 + 1] = a.y + bs1[k0 + 1];
        hxb[k0 + 2] = a.z + bs1[k0 + 2];
        hxb[k0 + 3] = a.w + bs1[k0 + 3];
    }
    float w2[32];
#pragma unroll
    for (int k = 0; k < 32; k++) w2[k] = Ws2[k];       // uniform -> s_load
    const float bbias = bs2[0];

    float acc = 0.f;
    for (int j = s; j < nb; j += 8) {
        const float4* hr4 = (const float4*)(hyS + j * 36);
        float d0 = bbias, d1 = 0.f, d2 = 0.f, d3 = 0.f;
#pragma unroll
        for (int kk = 0; kk < 8; kk++) {
            const float4 h = hr4[kk];
            const int k0 = 4 * kk;
            d0 = fmaf(fmaxf(hxb[k0 + 0] + h.x, 0.f), w2[k0 + 0], d0);
            d1 = fmaf(fmaxf(hxb[k0 + 1] + h.y, 0.f), w2[k0 + 1], d1);
            d2 = fmaf(fmaxf(hxb[k0 + 2] + h.z, 0.f), w2[k0 + 2], d2);
            d3 = fmaf(fmaxf(hxb[k0 + 3] + h.w, 0.f), w2[k0 + 3], d3);
        }
        const float dd = (d0 + d1) + (d2 + d3);
        const float same = 1.f / (1.f + __expf(-dd));
        acc += fminf(isoS[j], same);
    }
    acc += __shfl_xor(acc, 1);
    acc += __shfl_xor(acc, 2);
    acc += __shfl_xor(acc, 4);

    const float denom = (float)(nb > 1 ? nb : 1);
    const float exists = acc / denom;
    const float outer = fmaxf(1.f - isoS[li], exists);
    float val = (li < nb) ? outer : 1.f;

    // min over the wave, then block
    val = fminf(val, __shfl_xor(val, 8));
    val = fminf(val, __shfl_xor(val, 16));
    val = fminf(val, __shfl_xor(val, 32));
    if ((t & 63) == 0) wred[t >> 6] = val;
    __syncthreads();

    if (t == 0) {
        float m = wred[0];
#pragma unroll
        for (int w = 1; w < 8; w++) m = fminf(m, wred[w]);
        ws[blockIdx.x] = m;
    }
}

// ---------------------------------------------------------------------------
// Finalize: 1 block x 128 threads. sat_b = min of the two half-mins; mean over
// valid batches. Dispatch boundary guarantees visibility of ws stores.
// ---------------------------------------------------------------------------
__global__ __launch_bounds__(128) void finalize_kernel(
    const int* __restrict__ num_objects, const float* __restrict__ ws,
    float* __restrict__ out)
{
    __shared__ float r1[2], r2[2];
    const int t = threadIdx.x;        // 0..127 = batch
    const float sat = fminf(ws[2 * t], ws[2 * t + 1]);
    const float valid = (num_objects[t] > 0) ? 1.f : 0.f;
    float contrib = sat * valid;
    float vcnt = valid;
#pragma unroll
    for (int off = 1; off < 64; off <<= 1) {
        contrib += __shfl_xor(contrib, off);
        vcnt    += __shfl_xor(vcnt, off);
    }
    if ((t & 63) == 0) { r1[t >> 6] = contrib; r2[t >> 6] = vcnt; }
    __syncthreads();
    if (t == 0) {
        const float sc = r1[0] + r1[1];
        const float cn = r2[0] + r2[1];
        out[0] = (cn > 0.f) ? (sc / cn) : 1.f;
    }
}

extern "C" void kernel_launch(void* const* d_in, const int* in_sizes, int n_in,
                              void* d_out, int out_size, void* d_ws, size_t ws_size,
                              hipStream_t stream)
{
    const float* boxes       = (const float*)d_in[0];
    const int*   classes     = (const int*)d_in[1];
    const float* scores      = (const float*)d_in[2];
    const int*   num_objects = (const int*)d_in[3];
    const float* W1  = (const float*)d_in[4];
    const float* b1  = (const float*)d_in[5];
    const float* W2  = (const float*)d_in[6];
    const float* b2  = (const float*)d_in[7];
    const float* Wo1 = (const float*)d_in[8];
    const float* bo1 = (const float*)d_in[9];
    const float* Wo2 = (const float*)d_in[10];
    const float* bo2 = (const float*)d_in[11];
    const float* Ws1 = (const float*)d_in[12];
    const float* bs1 = (const float*)d_in[13];
    const float* Ws2 = (const float*)d_in[14];
    const float* bs2 = (const float*)d_in[15];

    float* ws  = (float*)d_ws;
    float* out = (float*)d_out;

    ltn_fused<<<256, 512, 0, stream>>>(boxes, classes, scores, num_objects,
                                       W1, b1, W2, b2, Wo1, bo1, Wo2, bo2,
                                       Ws1, bs1, Ws2, bs2, ws);
    finalize_kernel<<<1, 128, 0, stream>>>(num_objects, ws, out);
}

// Round 10
// 99.079 us; speedup vs baseline: 1.0534x; 1.0148x over previous
//
#include <hip/hip_runtime.h>

#define BB 128
#define NN 128
#define EE 32

// ws: float block-min slots [0..255], slot = blockIdx.x of ltn_fused
// (= b*2 + half). finalize_kernel (2nd dispatch) reduces them; dispatch
// boundary guarantees visibility. No atomics, no ws init needed.

// ---------------------------------------------------------------------------
// Fused: grid 256 = 128 b x 2 i-halves; block 512 = 16 groups x 32 lanes
// (8 waves -> 2 waves/SIMD).
// Phase A (encode, 2x redundant chip-wide): lane e owns neuron e; weight
// COLUMNS in VGPRs (loaded once); h1/enc broadcast via 2 alternating private
// LDS rows per group; each group encodes 8 items -> hyS (all), hxS (own half),
// isoS.
// Phase B (pairs): TWO i's per lane (p = t>>4 -> 32 pairs x 16 j-lanes); each
// hy-row ds_read_b128 feeds both i's fma chains (halves LDS-pipe traffic vs
// r9's 1-i/lane).
// Phase C: block min -> plain store ws[blockIdx.x].
// ---------------------------------------------------------------------------
__global__ __launch_bounds__(512) void ltn_fused(
    const float* __restrict__ boxes, const int* __restrict__ classes,
    const float* __restrict__ scores, const int* __restrict__ num_objects,
    const float* __restrict__ W1, const float* __restrict__ b1,
    const float* __restrict__ W2, const float* __restrict__ b2,
    const float* __restrict__ Wo1, const float* __restrict__ bo1,
    const float* __restrict__ Wo2, const float* __restrict__ bo2,
    const float* __restrict__ Ws1, const float* __restrict__ bs1,
    const float* __restrict__ Ws2, const float* __restrict__ bs2,
    float* __restrict__ ws)
{
    __shared__ float hyS[128 * 36];   // stride 36: rows 16B-aligned, conflict-free
    __shared__ float hxS[64 * 36];    // own half's i-rows only
    __shared__ float rows[32 * 36];   // 2 scratch rows per group (sw-pipeline)
    __shared__ float isoS[128];
    __shared__ float wred[8];

    const int t = threadIdx.x;
    const int b = blockIdx.x >> 1;
    const int half = blockIdx.x & 1;
    const int e = t & 31;
    const int g = t >> 5;              // group 0..15

    const int nb = num_objects[b];     // early: hide latency behind Phase A

    // ---- weight columns into VGPRs (coalesced dword loads, once) ----
    float w1c[6];
#pragma unroll
    for (int f = 0; f < 6; f++) w1c[f] = W1[f * 32 + e];
    float w2c[32], wo1c[32], wsxc[32], wsyc[32];
#pragma unroll
    for (int k = 0; k < 32; k++) {
        w2c[k]  = W2[k * 32 + e];
        wo1c[k] = Wo1[k * 32 + e];
        wsxc[k] = Ws1[k * 32 + e];
        wsyc[k] = Ws1[(32 + k) * 32 + e];
    }
    const float b1e  = b1[e];
    const float b2e  = b2[e];
    const float bo1e = bo1[e];
    const float wo2e = Wo2[e];
    const float bo2s = bo2[0];

    // ---------------- Phase A: encode 8 items per group ----------------
    const int il0 = g * 8;
#pragma unroll 2
    for (int it = 0; it < 8; ++it) {
        const int il = il0 + it;               // local item 0..127
        const int item = b * 128 + il;
        float* row = rows + (g * 2 + (it & 1)) * 36;

        const float4 bx = ((const float4*)boxes)[item];
        const float c4 = (float)classes[item];
        const float c5 = scores[item];

        // layer 1
        float h1 = b1e;
        h1 = fmaf(bx.x, w1c[0], h1);
        h1 = fmaf(bx.y, w1c[1], h1);
        h1 = fmaf(bx.z, w1c[2], h1);
        h1 = fmaf(bx.w, w1c[3], h1);
        h1 = fmaf(c4,   w1c[4], h1);
        h1 = fmaf(c5,   w1c[5], h1);
        h1 = fmaxf(h1, 0.f);

        row[e] = h1;                           // ds_write_b32

        // layer 2: enc = h1 @ W2 + b2 (broadcast reads, 4 chains)
        float a0 = 0.f, a1 = 0.f, a2 = 0.f, a3 = 0.f;
#pragma unroll
        for (int kk = 0; kk < 8; kk++) {
            const float4 h = *(const float4*)(row + kk * 4);
            a0 = fmaf(h.x, w2c[4 * kk + 0], a0);
            a1 = fmaf(h.y, w2c[4 * kk + 1], a1);
            a2 = fmaf(h.z, w2c[4 * kk + 2], a2);
            a3 = fmaf(h.w, w2c[4 * kk + 3], a3);
        }
        const float enc = ((a0 + a1) + (a2 + a3)) + b2e;
        row[e] = enc;   // wave order: all h1 reads above already issued

        // heads
        float u = bo1e, hx = 0.f, hy = 0.f;
#pragma unroll
        for (int kk = 0; kk < 8; kk++) {
            const float4 ec = *(const float4*)(row + kk * 4);
            const int k0 = 4 * kk;
            u  = fmaf(ec.x, wo1c[k0 + 0], u);
            u  = fmaf(ec.y, wo1c[k0 + 1], u);
            u  = fmaf(ec.z, wo1c[k0 + 2], u);
            u  = fmaf(ec.w, wo1c[k0 + 3], u);
            hx = fmaf(ec.x, wsxc[k0 + 0], hx);
            hx = fmaf(ec.y, wsxc[k0 + 1], hx);
            hx = fmaf(ec.z, wsxc[k0 + 2], hx);
            hx = fmaf(ec.w, wsxc[k0 + 3], hx);
            hy = fmaf(ec.x, wsyc[k0 + 0], hy);
            hy = fmaf(ec.y, wsyc[k0 + 1], hy);
            hy = fmaf(ec.z, wsyc[k0 + 2], hy);
            hy = fmaf(ec.w, wsyc[k0 + 3], hy);
        }
        u = fmaxf(u, 0.f);

        float v = u * wo2e;
        v += __shfl_xor(v, 16, 32);
        v += __shfl_xor(v, 8, 32);
        v += __shfl_xor(v, 4, 32);
        v += __shfl_xor(v, 2, 32);
        v += __shfl_xor(v, 1, 32);

        hyS[il * 36 + e] = hy;
        if ((il >> 6) == half) hxS[(il & 63) * 36 + e] = hx;
        if (e == 0)
            isoS[il] = 1.f / (1.f + __expf(-(v + bo2s)));
    }
    __syncthreads();

    // ---------------- Phase B: pairs (2 i's per lane, 16 j-lanes) --------
    const int p  = t >> 4;             // 0..31 i-pair within half
    const int li0 = half * 64 + 2 * p; // local i (for isoS)
    const int li1 = li0 + 1;
    const int s  = t & 15;

    float hxb0[32], hxb1[32];
#pragma unroll
    for (int kk = 0; kk < 8; kk++) {
        const float4 a = ((const float4*)(hxS + (2 * p) * 36))[kk];
        const float4 c = ((const float4*)(hxS + (2 * p + 1) * 36))[kk];
        const int k0 = 4 * kk;
        hxb0[k0 + 0] = a.x + bs1[k0 + 0];  hxb1[k0 + 0] = c.x + bs1[k0 + 0];
        hxb0[k0 + 1] = a.y + bs1[k0 + 1];  hxb1[k0 + 1] = c.y + bs1[k0 + 1];
        hxb0[k0 + 2] = a.z + bs1[k0 + 2];  hxb1[k0 + 2] = c.z + bs1[k0 + 2];
        hxb0[k0 + 3] = a.w + bs1[k0 + 3];  hxb1[k0 + 3] = c.w + bs1[k0 + 3];
    }
    float w2[32];
#pragma unroll
    for (int k = 0; k < 32; k++) w2[k] = Ws2[k];       // uniform -> s_load
    const float bbias = bs2[0];

    float acc0 = 0.f, acc1 = 0.f;
    for (int j = s; j < nb; j += 16) {
        const float4* hr4 = (const float4*)(hyS + j * 36);
        float d0 = bbias, d1 = 0.f, d2 = 0.f, d3 = 0.f;
        float e0 = bbias, e1 = 0.f, e2 = 0.f, e3 = 0.f;
#pragma unroll
        for (int kk = 0; kk < 8; kk++) {
            const float4 h = hr4[kk];     // one b128 read feeds both i's
            const int k0 = 4 * kk;
            d0 = fmaf(fmaxf(hxb0[k0 + 0] + h.x, 0.f), w2[k0 + 0], d0);
            d1 = fmaf(fmaxf(hxb0[k0 + 1] + h.y, 0.f), w2[k0 + 1], d1);
            d2 = fmaf(fmaxf(hxb0[k0 + 2] + h.z, 0.f), w2[k0 + 2], d2);
            d3 = fmaf(fmaxf(hxb0[k0 + 3] + h.w, 0.f), w2[k0 + 3], d3);
            e0 = fmaf(fmaxf(hxb1[k0 + 0] + h.x, 0.f), w2[k0 + 0], e0);
            e1 = fmaf(fmaxf(hxb1[k0 + 1] + h.y, 0.f), w2[k0 + 1], e1);
            e2 = fmaf(fmaxf(hxb1[k0 + 2] + h.z, 0.f), w2[k0 + 2], e2);
            e3 = fmaf(fmaxf(hxb1[k0 + 3] + h.w, 0.f), w2[k0 + 3], e3);
        }
        const float dd = (d0 + d1) + (d2 + d3);
        const float ee = (e0 + e1) + (e2 + e3);
        const float same0 = 1.f / (1.f + __expf(-dd));
        const float same1 = 1.f / (1.f + __expf(-ee));
        const float iso_j = isoS[j];
        acc0 += fminf(iso_j, same0);
        acc1 += fminf(iso_j, same1);
    }
    // sum over the 16 j-lanes of this pair
    acc0 += __shfl_xor(acc0, 1);  acc1 += __shfl_xor(acc1, 1);
    acc0 += __shfl_xor(acc0, 2);  acc1 += __shfl_xor(acc1, 2);
    acc0 += __shfl_xor(acc0, 4);  acc1 += __shfl_xor(acc1, 4);
    acc0 += __shfl_xor(acc0, 8);  acc1 += __shfl_xor(acc1, 8);

    const float denom = (float)(nb > 1 ? nb : 1);
    const float ex0 = acc0 / denom;
    const float ex1 = acc1 / denom;
    const float o0 = fmaxf(1.f - isoS[li0], ex0);
    const float o1 = fmaxf(1.f - isoS[li1], ex1);
    float val = fminf((li0 < nb) ? o0 : 1.f, (li1 < nb) ? o1 : 1.f);

    // min over the wave (4 pair-groups), then block
    val = fminf(val, __shfl_xor(val, 16));
    val = fminf(val, __shfl_xor(val, 32));
    if ((t & 63) == 0) wred[t >> 6] = val;
    __syncthreads();

    if (t == 0) {
        float m = wred[0];
#pragma unroll
        for (int w = 1; w < 8; w++) m = fminf(m, wred[w]);
        ws[blockIdx.x] = m;
    }
}

// ---------------------------------------------------------------------------
// Finalize: 1 block x 128 threads. sat_b = min of the two half-mins; mean over
// valid batches. Dispatch boundary guarantees visibility of ws stores.
// ---------------------------------------------------------------------------
__global__ __launch_bounds__(128) void finalize_kernel(
    const int* __restrict__ num_objects, const float* __restrict__ ws,
    float* __restrict__ out)
{
    __shared__ float r1[2], r2[2];
    const int t = threadIdx.x;        // 0..127 = batch
    const float sat = fminf(ws[2 * t], ws[2 * t + 1]);
    const float valid = (num_objects[t] > 0) ? 1.f : 0.f;
    float contrib = sat * valid;
    float vcnt = valid;
#pragma unroll
    for (int off = 1; off < 64; off <<= 1) {
        contrib += __shfl_xor(contrib, off);
        vcnt    += __shfl_xor(vcnt, off);
    }
    if ((t & 63) == 0) { r1[t >> 6] = contrib; r2[t >> 6] = vcnt; }
    __syncthreads();
    if (t == 0) {
        const float sc = r1[0] + r1[1];
        const float cn = r2[0] + r2[1];
        out[0] = (cn > 0.f) ? (sc / cn) : 1.f;
    }
}

extern "C" void kernel_launch(void* const* d_in, const int* in_sizes, int n_in,
                              void* d_out, int out_size, void* d_ws, size_t ws_size,
                              hipStream_t stream)
{
    const float* boxes       = (const float*)d_in[0];
    const int*   classes     = (const int*)d_in[1];
    const float* scores      = (const float*)d_in[2];
    const int*   num_objects = (const int*)d_in[3];
    const float* W1  = (const float*)d_in[4];
    const float* b1  = (const float*)d_in[5];
    const float* W2  = (const float*)d_in[6];
    const float* b2  = (const float*)d_in[7];
    const float* Wo1 = (const float*)d_in[8];
    const float* bo1 = (const float*)d_in[9];
    const float* Wo2 = (const float*)d_in[10];
    const float* bo2 = (const float*)d_in[11];
    const float* Ws1 = (const float*)d_in[12];
    const float* bs1 = (const float*)d_in[13];
    const float* Ws2 = (const float*)d_in[14];
    const float* bs2 = (const float*)d_in[15];

    float* ws  = (float*)d_ws;
    float* out = (float*)d_out;

    ltn_fused<<<256, 512, 0, stream>>>(boxes, classes, scores, num_objects,
                                       W1, b1, W2, b2, Wo1, bo1, Wo2, bo2,
                                       Ws1, bs1, Ws2, bs2, ws);
    finalize_kernel<<<1, 128, 0, stream>>>(num_objects, ws, out);
}